// Round 1
// baseline (6765.210 us; speedup 1.0000x reference)
//
#include <hip/hip_runtime.h>
#include <hip/hip_fp16.h>

#define BB 8
#define SS 4096
#define II 512
#define HH 512

typedef _Float16 h2_t __attribute__((ext_vector_type(2)));

__device__ __forceinline__ unsigned int pack_h2(float a, float b) {
    h2_t p;
    p.x = (_Float16)a;
    p.y = (_Float16)b;
    return __builtin_bit_cast(unsigned int, p);
}

__device__ __forceinline__ float dot2acc(unsigned int hp, unsigned int wp, float acc) {
#if __has_builtin(__builtin_amdgcn_fdot2)
    return __builtin_amdgcn_fdot2(__builtin_bit_cast(h2_t, hp),
                                  __builtin_bit_cast(h2_t, wp), acc, false);
#else
    h2_t h = __builtin_bit_cast(h2_t, hp);
    h2_t w = __builtin_bit_cast(h2_t, wp);
    acc = fmaf((float)h.x, (float)w.x, acc);
    acc = fmaf((float)h.y, (float)w.y, acc);
    return acc;
#endif
}

__device__ __forceinline__ float tanh_fast(float x) {
    float ax = fabsf(x);
    float t  = exp2f(-2.8853900817779268f * ax);   // e^{-2|x|}
    float r  = (1.0f - t) * __builtin_amdgcn_rcpf(1.0f + t);
    return copysignf(r, x);
}

// ---------------------------------------------------------------------------
// Phase 1: xp[m][n] = sum_k x[m][k] * W_ih[n][k] + b_ih[n]   (M=32768,N=512,K=512)
// Simple fp32 LDS-tiled GEMM, 64x64 tile, 256 threads, k-major LDS tiles.
// ---------------------------------------------------------------------------
#define P1_TM 64
#define P1_TN 64
#define P1_TK 16
#define P1_LDP 68   // LDS pitch in floats (bank-conflict-avoiding, 16B-aligned rows)

__global__ __launch_bounds__(256) void xp_gemm(const float* __restrict__ x,
                                               const float* __restrict__ wih,
                                               const float* __restrict__ bih,
                                               float* __restrict__ out) {
    __shared__ float As[P1_TK][P1_LDP];
    __shared__ float Bs[P1_TK][P1_LDP];
    const int tid = threadIdx.x;
    const int n0  = blockIdx.x * P1_TN;
    const int m0  = blockIdx.y * P1_TM;
    const int row = tid >> 2;   // 0..63
    const int f4  = tid & 3;    // 0..3  (which 4-float chunk of the 16-wide k-slab)
    const int ty  = tid >> 4;   // 0..15 (m quad)
    const int tx  = tid & 15;   // 0..15 (n quad)

    float acc[4][4];
#pragma unroll
    for (int r = 0; r < 4; ++r)
#pragma unroll
        for (int c = 0; c < 4; ++c) acc[r][c] = 0.0f;

    const float* xa = x   + (size_t)(m0 + row) * II + f4 * 4;
    const float* wb = wih + (size_t)(n0 + row) * II + f4 * 4;

    for (int kb = 0; kb < II; kb += P1_TK) {
        float4 av = *(const float4*)(xa + kb);
        float4 bv = *(const float4*)(wb + kb);
        __syncthreads();
        As[f4 * 4 + 0][row] = av.x; As[f4 * 4 + 1][row] = av.y;
        As[f4 * 4 + 2][row] = av.z; As[f4 * 4 + 3][row] = av.w;
        Bs[f4 * 4 + 0][row] = bv.x; Bs[f4 * 4 + 1][row] = bv.y;
        Bs[f4 * 4 + 2][row] = bv.z; Bs[f4 * 4 + 3][row] = bv.w;
        __syncthreads();
#pragma unroll
        for (int kk = 0; kk < P1_TK; ++kk) {
            const float* a4 = &As[kk][ty * 4];
            const float* b4 = &Bs[kk][tx * 4];
#pragma unroll
            for (int r = 0; r < 4; ++r)
#pragma unroll
                for (int c = 0; c < 4; ++c)
                    acc[r][c] = fmaf(a4[r], b4[c], acc[r][c]);
        }
    }

    const float4 bias = *(const float4*)&bih[n0 + tx * 4];
#pragma unroll
    for (int r = 0; r < 4; ++r) {
        float4 v;
        v.x = acc[r][0] + bias.x;
        v.y = acc[r][1] + bias.y;
        v.z = acc[r][2] + bias.z;
        v.w = acc[r][3] + bias.w;
        *(float4*)(out + (size_t)(m0 + ty * 4 + r) * HH + n0 + tx * 4) = v;
    }
}

// ---------------------------------------------------------------------------
// Phase 2: sequential scan. One workgroup (512 threads, 1 CU) per batch chain.
// Thread j owns output row j of W_hh: cols [0,384) in 192 packed-fp16 VGPRs,
// cols [384,512) in LDS (row-major, 66-dword pitch). h kept packed-fp16 in LDS.
// ---------------------------------------------------------------------------
#define KREG 384
#define NREG (KREG / 2)     // 192 packed dwords in regs
#define KLDS (HH - KREG)    // 128 cols in LDS
#define W2P  66             // LDS pitch in dwords per W row (8B-aligned rows)
#define LDS_DW (256 + HH * W2P)

__global__ __launch_bounds__(512, 2) void rnn_scan(const float* __restrict__ whh,
                                                   const float* __restrict__ bhh,
                                                   float* __restrict__ io) {
    extern __shared__ unsigned int lds[];
    unsigned int* hbuf = lds;        // 256 dwords: h as 512 packed fp16
    unsigned int* w2   = lds + 256;  // HH rows x W2P dwords

    const int b = blockIdx.x;
    const int j = threadIdx.x;

    // W row j, cols [0,KREG) -> registers as packed fp16 pairs
    unsigned int wreg[NREG];
    const float* wrow = whh + (size_t)j * HH;
#pragma unroll
    for (int q4 = 0; q4 < KREG / 4; ++q4) {
        float4 f = *(const float4*)(wrow + q4 * 4);
        wreg[2 * q4 + 0] = pack_h2(f.x, f.y);
        wreg[2 * q4 + 1] = pack_h2(f.z, f.w);
    }

    // W cols [KREG, 512) -> LDS, cooperatively
    for (int idx = j; idx < HH * (KLDS / 2); idx += 512) {
        int jj = idx >> 6;   // row
        int q  = idx & 63;   // pair index within row
        const float* p = whh + (size_t)jj * HH + KREG + 2 * q;
        w2[jj * W2P + q] = pack_h2(p[0], p[1]);
    }
    if (j < 256) hbuf[j] = 0u;   // h0 = 0
    const float bj = bhh[j];
    __syncthreads();

    float* iob = io + (size_t)b * SS * HH;
    float xp_cur = iob[j];
    const unsigned int* wl = w2 + j * W2P;

#pragma unroll 1
    for (int t = 0; t < SS; ++t) {
        const int tn = (t + 1 < SS) ? t + 1 : t;
        float xp_next = iob[(size_t)tn * HH + j];

        float a0 = xp_cur + bj, a1 = 0.0f, a2 = 0.0f, a3 = 0.0f;

        // k in [0, 384): h broadcast from LDS, W from registers
#pragma unroll
        for (int c = 0; c < NREG / 4; ++c) {          // 48 chunks of 8 k
            uint4 hv = *(const uint4*)&hbuf[4 * c];
            a0 = dot2acc(hv.x, wreg[4 * c + 0], a0);
            a1 = dot2acc(hv.y, wreg[4 * c + 1], a1);
            a2 = dot2acc(hv.z, wreg[4 * c + 2], a2);
            a3 = dot2acc(hv.w, wreg[4 * c + 3], a3);
        }
        // k in [384, 512): h broadcast, W from LDS (b64 reads)
#pragma unroll
        for (int c = 0; c < (KLDS / 2) / 4; ++c) {    // 16 chunks of 8 k
            uint4 hv = *(const uint4*)&hbuf[NREG + 4 * c];
            uint2 wa = *(const uint2*)&wl[4 * c];
            uint2 wc = *(const uint2*)&wl[4 * c + 2];
            a0 = dot2acc(hv.x, wa.x, a0);
            a1 = dot2acc(hv.y, wa.y, a1);
            a2 = dot2acc(hv.z, wc.x, a2);
            a3 = dot2acc(hv.w, wc.y, a3);
        }

        float hnew = tanh_fast((a0 + a1) + (a2 + a3));
        iob[(size_t)t * HH + j] = hnew;     // overwrite xp[t] with h[t]
        __syncthreads();                    // all reads of h(t-1) done
        ((_Float16*)hbuf)[j] = (_Float16)hnew;
        __syncthreads();                    // h(t) visible to all
        xp_cur = xp_next;
    }
}

// ---------------------------------------------------------------------------
extern "C" void kernel_launch(void* const* d_in, const int* in_sizes, int n_in,
                              void* d_out, int out_size, void* d_ws, size_t ws_size,
                              hipStream_t stream) {
    const float* x   = (const float*)d_in[0];
    const float* wih = (const float*)d_in[1];
    const float* whh = (const float*)d_in[2];
    const float* bih = (const float*)d_in[3];
    const float* bhh = (const float*)d_in[4];
    float* out = (float*)d_out;

    dim3 g1(HH / P1_TN, (BB * SS) / P1_TM);   // (8, 512)
    xp_gemm<<<g1, 256, 0, stream>>>(x, wih, bih, out);

    static_assert(LDS_DW * 4 <= 163840, "LDS over 160 KiB");
    hipFuncSetAttribute((const void*)rnn_scan,
                        hipFuncAttributeMaxDynamicSharedMemorySize, LDS_DW * 4);
    rnn_scan<<<dim3(BB), dim3(512), LDS_DW * 4, stream>>>(whh, bhh, out);
}